// Round 4
// baseline (86.609 us; speedup 1.0000x reference)
//
#include <hip/hip_runtime.h>
#include <math.h>

#define NO_CH   144      // 4*16 + 80
#define NC      80
#define REGMAX  16
#define A_TOT   8400     // 80*80 + 40*40 + 20*20
#define HW0     6400
#define HW1     1600
#define HW2     400
#define SC_BLOCKS 132    // ceil(8400/64) -- 64-anchor tiles never straddle levels

__device__ __forceinline__ float rcpf(float x) { return __builtin_amdgcn_rcpf(x); }
__device__ __forceinline__ float sigmoidf(float x) {
    return rcpf(1.0f + __expf(-x));
}

// ---------------------------------------------------------------------------
// One block = 64 anchors of one batch: boxes (DFL) + scores.
//  phase 1: wave = DFL group. lane = (rquad 0..3, anchor-quad 0..15).
//           4 float4 loads/lane (4 channels x 4 anchors), no-max exp,
//           se/sw float4 accumulators, 2-step shfl_xor(16,32) butterfly
//           over the channel axis -> dist float4 -> 1KB LDS strip.
//  phase 2: scores float4 loads -> sigmoid -> LDS tile (stride 65).
//  single __syncthreads(), outputs stream out nontemporally.
// ---------------------------------------------------------------------------
__global__ __launch_bounds__(256, 6) void fused_kernel(
    const float* __restrict__ f0, const float* __restrict__ f1,
    const float* __restrict__ f2, float* __restrict__ out_boxes,
    float* __restrict__ out_scores)
{
    __shared__ float tile[NC][65];     // 20.8 KB
    __shared__ float dist_lds[4][64];  // 1 KB (unpadded: float4-aligned rows)

    const int b   = blockIdx.y;
    const int a0  = blockIdx.x * 64;
    const int tid = threadIdx.x;

    const float* base; int hw, local; float st;
    if (a0 < HW0) {
        base = f0 + (size_t)b * NO_CH * HW0; hw = HW0; local = a0; st = 8.0f;
    } else if (a0 < HW0 + HW1) {
        base = f1 + (size_t)b * NO_CH * HW1; hw = HW1; local = a0 - HW0; st = 16.0f;
    } else {
        base = f2 + (size_t)b * NO_CH * HW2; hw = HW2; local = a0 - (HW0 + HW1); st = 32.0f;
    }

    const int nvalid = min(64, A_TOT - a0);

    // ---- phase 1: DFL expectation ----
    {
        const int g    = tid >> 6;       // wave = group
        const int lane = tid & 63;
        const int laq  = lane & 15;      // anchor quad (4 anchors)
        const int rq   = lane >> 4;      // channel quad within group (0..3)

        float4 se = make_float4(0.f, 0.f, 0.f, 0.f);
        float4 sw = make_float4(0.f, 0.f, 0.f, 0.f);

        if (laq * 4 < nvalid) {
            const float* s = base + (size_t)(g * REGMAX + rq * 4) * hw + local + laq * 4;
            #pragma unroll
            for (int r = 0; r < 4; ++r) {
                const float4 v = *reinterpret_cast<const float4*>(s + (size_t)r * hw);
                const float wgt = (float)(rq * 4 + r);
                const float ex = __expf(v.x);
                const float ey = __expf(v.y);
                const float ez = __expf(v.z);
                const float ew = __expf(v.w);
                se.x += ex; se.y += ey; se.z += ez; se.w += ew;
                sw.x += ex * wgt; sw.y += ey * wgt; sw.z += ez * wgt; sw.w += ew * wgt;
            }
        }
        // butterfly over rq (lane bits 4,5): sums the 16 channels per anchor
        #pragma unroll
        for (int m = 16; m <= 32; m <<= 1) {
            se.x += __shfl_xor(se.x, m, 64);
            se.y += __shfl_xor(se.y, m, 64);
            se.z += __shfl_xor(se.z, m, 64);
            se.w += __shfl_xor(se.w, m, 64);
            sw.x += __shfl_xor(sw.x, m, 64);
            sw.y += __shfl_xor(sw.y, m, 64);
            sw.z += __shfl_xor(sw.z, m, 64);
            sw.w += __shfl_xor(sw.w, m, 64);
        }
        if (rq == 0 && laq * 4 < nvalid) {
            const float4 dist = make_float4(sw.x * rcpf(se.x), sw.y * rcpf(se.y),
                                            sw.z * rcpf(se.z), sw.w * rcpf(se.w));
            *reinterpret_cast<float4*>(&dist_lds[g][laq * 4]) = dist;
        }
    }

    // ---- phase 2: scores sigmoid into LDS tile ----
    const float* ssc = base + (size_t)(4 * REGMAX) * hw + local;
    if (nvalid == 64) {
        const int quad = tid & 15;     // float4 slot within the 64-anchor row
        const int r0   = tid >> 4;     // 0..15
        #pragma unroll
        for (int i = 0; i < 5; ++i) {
            const int r = r0 + 16 * i;
            const float4 v = *reinterpret_cast<const float4*>(
                ssc + (size_t)r * hw + quad * 4);
            tile[r][quad * 4 + 0] = sigmoidf(v.x);
            tile[r][quad * 4 + 1] = sigmoidf(v.y);
            tile[r][quad * 4 + 2] = sigmoidf(v.z);
            tile[r][quad * 4 + 3] = sigmoidf(v.w);
        }
    } else {
        const int col = tid & 63;
        const int r0  = tid >> 6;      // 0..3
        if (col < nvalid) {
            #pragma unroll
            for (int i = 0; i < 20; ++i) {
                const int r = r0 + 4 * i;
                tile[r][col] = sigmoidf(ssc[(size_t)r * hw + col]);
            }
        }
    }

    __syncthreads();

    // ---- boxes out: 4*nvalid contiguous floats, one per thread ----
    if (tid < 4 * nvalid) {
        const int la   = tid >> 2;
        const int comp = tid & 3;
        const int gl   = local + la;
        int ix, iy;
        if (hw == HW0)      { iy = gl / 80; ix = gl - iy * 80; }
        else if (hw == HW1) { iy = gl / 40; ix = gl - iy * 40; }
        else                { iy = gl / 20; ix = gl - iy * 20; }
        const float axy = ((comp & 1) ? (float)iy : (float)ix) + 0.5f;
        const float d   = dist_lds[comp][la];
        const float val = (axy + ((comp >= 2) ? d : -d)) * st;
        __builtin_nontemporal_store(
            val, out_boxes + ((size_t)b * A_TOT + a0) * 4 + tid);
    }

    // ---- scores out: transposed, contiguous & coalesced ----
    float* dst = out_scores + ((size_t)b * A_TOT + a0) * NC;
    const int total = nvalid * NC;
    for (int j = tid; j < total; j += 256) {
        const int la = j / NC;
        const int c  = j - la * NC;
        __builtin_nontemporal_store(tile[c][la], dst + j);  // 65-stride: conflict-free
    }
}

extern "C" void kernel_launch(void* const* d_in, const int* in_sizes, int n_in,
                              void* d_out, int out_size, void* d_ws, size_t ws_size,
                              hipStream_t stream) {
    const float* f0 = (const float*)d_in[0];
    const float* f1 = (const float*)d_in[1];
    const float* f2 = (const float*)d_in[2];

    const int b = in_sizes[0] / (NO_CH * HW0);   // 64

    float* out_boxes  = (float*)d_out;
    float* out_scores = out_boxes + (size_t)b * A_TOT * 4;

    dim3 grid(SC_BLOCKS, b);
    fused_kernel<<<grid, dim3(256), 0, stream>>>(f0, f1, f2, out_boxes, out_scores);
}